// Round 1
// baseline (296.028 us; speedup 1.0000x reference)
//
#include <hip/hip_runtime.h>

#define TT 50
#define TPAD 52          // padded to multiple of 4 for float4 loop
#define START_TAG 48
#define STOP_TAG 49
#define BB 1024
#define LL 512
#define NEGV -10000.0f

// ---------------- forward (partition) kernel: one wave per sequence ----------
__global__ __launch_bounds__(64) void crf_forward(
    const float* __restrict__ logits,   // [B, L, T]
    const float* __restrict__ trans,    // [T, T]
    const int* __restrict__ lens,       // [B]
    float* __restrict__ part_out)       // [B]
{
    const int b    = blockIdx.x;
    const int lane = threadIdx.x;
    const int len  = lens[b];

    __shared__ __align__(16) float lds_e[64];

    // Precompute exp(trans) row `lane` into registers (constant over t).
    float Mrow[TPAD];
#pragma unroll
    for (int j = 0; j < TPAD; ++j) Mrow[j] = 0.0f;
    if (lane < TT) {
        for (int j = 0; j < TT; ++j) Mrow[j] = __expf(trans[lane * TT + j]);
    }

    // alpha init: start tag = 0, everything else effectively -inf.
    float alpha = (lane == START_TAG) ? 0.0f : -INFINITY;
    float m = 0.0f;   // max_j alpha[j] at t=0

    const size_t base = (size_t)b * LL;

    // prefetch logits, distance 2
    float lgA = 0.0f, lgB = 0.0f;
    if (lane < TT) {
        if (len > 0) lgA = logits[(base + 0) * TT + lane];
        if (len > 1) lgB = logits[(base + 1) * TT + lane];
    }

    for (int t = 0; t < len; ++t) {
        float e = __expf(alpha - m);     // lanes >= TT and START row give 0
        lds_e[lane] = e;
        __syncthreads();

        float lg = lgA;
        lgA = lgB;
        if (lane < TT && t + 2 < len) lgB = logits[(base + t + 2) * TT + lane];

        float s0 = 0.f, s1 = 0.f, s2 = 0.f, s3 = 0.f;
#pragma unroll
        for (int jj = 0; jj < TPAD / 4; ++jj) {
            float4 ev = *reinterpret_cast<const float4*>(&lds_e[jj * 4]);
            s0 = fmaf(Mrow[jj * 4 + 0], ev.x, s0);
            s1 = fmaf(Mrow[jj * 4 + 1], ev.y, s1);
            s2 = fmaf(Mrow[jj * 4 + 2], ev.z, s2);
            s3 = fmaf(Mrow[jj * 4 + 3], ev.w, s3);
        }
        float s = (s0 + s1) + (s2 + s3);

        float na = lg + m + __logf(s);   // log(0) = -inf for START row: benign
        alpha = (lane < TT) ? na : -INFINITY;

        // exact max for next step
        float mn = alpha;
#pragma unroll
        for (int o = 32; o > 0; o >>= 1) mn = fmaxf(mn, __shfl_xor(mn, o));
        m = mn;
        __syncthreads();   // protect lds_e before next iteration's write
    }

    // partition = logsumexp_i(alpha[i] + trans[STOP, i])
    float v = (lane < TT) ? alpha + trans[STOP_TAG * TT + lane] : -INFINITY;
    float mm = v;
#pragma unroll
    for (int o = 32; o > 0; o >>= 1) mm = fmaxf(mm, __shfl_xor(mm, o));
    float ex = __expf(v - mm);           // -inf - finite = -inf -> 0
    float ssum = ex;
#pragma unroll
    for (int o = 32; o > 0; o >>= 1) ssum += __shfl_xor(ssum, o);
    if (lane == 0) part_out[b] = mm + __logf(ssum);
}

// ---------------- gold-path score (emission + transition) -------------------
__global__ __launch_bounds__(64) void crf_scores(
    const float* __restrict__ logits,
    const float* __restrict__ trans,
    const int* __restrict__ labels,     // [B, L]
    const int* __restrict__ lens,
    float* __restrict__ score_out)      // [B]
{
    const int b    = blockIdx.x;
    const int lane = threadIdx.x;
    const int len  = lens[b];

    float acc = 0.0f;
    for (int t = lane; t < len; t += 64) {
        int lab = labels[b * LL + t];
        acc += logits[((size_t)b * LL + t) * TT + lab];
        int prev = (t == 0) ? START_TAG : labels[b * LL + t - 1];
        acc += trans[lab * TT + prev];
    }
    if (lane == 0) acc += trans[STOP_TAG * TT + labels[b * LL + (len - 1)]];

#pragma unroll
    for (int o = 32; o > 0; o >>= 1) acc += __shfl_xor(acc, o);
    if (lane == 0) score_out[b] = acc;
}

// ---------------- final deterministic reduction ------------------------------
__global__ __launch_bounds__(1024) void crf_reduce(
    const float* __restrict__ part,
    const float* __restrict__ score,
    float* __restrict__ out)
{
    __shared__ float red[16];
    const int tid = threadIdx.x;
    float acc = part[tid] - score[tid];   // B == 1024 == blockDim
#pragma unroll
    for (int o = 32; o > 0; o >>= 1) acc += __shfl_xor(acc, o);
    const int w = tid >> 6;
    if ((tid & 63) == 0) red[w] = acc;
    __syncthreads();
    if (tid == 0) {
        float tot = 0.0f;
        for (int i = 0; i < 16; ++i) tot += red[i];
        out[0] = tot / (float)BB;
    }
}

extern "C" void kernel_launch(void* const* d_in, const int* in_sizes, int n_in,
                              void* d_out, int out_size, void* d_ws, size_t ws_size,
                              hipStream_t stream) {
    const float* logits = (const float*)d_in[0];
    const float* trans  = (const float*)d_in[1];
    const int*   labels = (const int*)d_in[2];
    const int*   lens   = (const int*)d_in[3];

    float* part  = (float*)d_ws;          // [B]
    float* score = part + BB;             // [B]
    float* out   = (float*)d_out;

    crf_forward<<<BB, 64, 0, stream>>>(logits, trans, lens, part);
    crf_scores<<<BB, 64, 0, stream>>>(logits, trans, labels, lens, score);
    crf_reduce<<<1, 1024, 0, stream>>>(part, score, out);
}

// Round 2
// 238.718 us; speedup vs baseline: 1.2401x; 1.2401x over previous
//
#include <hip/hip_runtime.h>

#define TT 50
#define TPAD 52          // padded to multiple of 4 for float4 loop
#define START_TAG 48
#define STOP_TAG 49
#define BB 1024
#define LL 512

// Rescale constants: multiply by 2^-64 / 2^+64, offset by 64*ln2.
#define UP_THR   0x1p63f
#define DOWN_THR 0x1p-32f
#define OFF_64LN2 44.3614195558364998f

// ---------------- forward (partition) kernel: one wave per sequence ----------
// Linear-domain recursion: e_{t+1} = exp(logit_t) * (M @ e_t), M = exp(trans).
// alpha_t = log(e_t) + moff. No transcendentals on the serial chain.
__global__ __launch_bounds__(64) void crf_forward(
    const float* __restrict__ logits,   // [B, L, T]
    const float* __restrict__ trans,    // [T, T]
    const int* __restrict__ lens,       // [B]
    float* __restrict__ part_out)       // [B]
{
    const int b    = blockIdx.x;
    const int lane = threadIdx.x;
    const int len  = lens[b];

    __shared__ __align__(16) float lds_e[64];

    // Precompute exp(trans) row `lane` into registers (constant over t).
    float Mrow[TPAD];
#pragma unroll
    for (int j = 0; j < TPAD; ++j) Mrow[j] = 0.0f;
    if (lane < TT) {
        for (int j = 0; j < TT; ++j) Mrow[j] = __expf(trans[lane * TT + j]);
    }

    // per-lane logits pointer (lanes >= TT clamp to a valid column; value unused)
    const int lane_c = (lane < TT) ? lane : (TT - 1);
    const float* pb = logits + (size_t)b * LL * TT + lane_c;

    // distance-4 prefetch pipeline (raw logits; exp applied at use time)
    float lgA = pb[(size_t)((0 < len) ? 0 : len - 1) * TT];
    float lgB = pb[(size_t)((1 < len) ? 1 : len - 1) * TT];
    float lgC = pb[(size_t)((2 < len) ? 2 : len - 1) * TT];
    float lgD = pb[(size_t)((3 < len) ? 3 : len - 1) * TT];

    // e = exp(alpha - moff): start tag carries mass 1, rest 0.
    float e    = (lane == START_TAG) ? 1.0f : 0.0f;
    float moff = 0.0f;

    for (int t = 0; t < len; ++t) {
        lds_e[lane] = e;
        asm volatile("s_waitcnt lgkmcnt(0)" ::: "memory");
        __builtin_amdgcn_wave_barrier();

        // rotate prefetch pipeline, issue t+4 (clamped; stays in flight, vmcnt>0)
        float lg = lgA; lgA = lgB; lgB = lgC; lgC = lgD;
        {
            int tp = t + 4; tp = (tp < len) ? tp : (len - 1);
            lgD = pb[(size_t)tp * TT];
        }
        float elg = __expf(lg);   // off the serial chain: input is 4 steps old

        float s0 = 0.f, s1 = 0.f, s2 = 0.f, s3 = 0.f;
#pragma unroll
        for (int jj = 0; jj < TPAD / 4; ++jj) {
            float4 ev = *reinterpret_cast<const float4*>(&lds_e[jj * 4]);
            s0 = fmaf(Mrow[jj * 4 + 0], ev.x, s0);
            s1 = fmaf(Mrow[jj * 4 + 1], ev.y, s1);
            s2 = fmaf(Mrow[jj * 4 + 2], ev.z, s2);
            s3 = fmaf(Mrow[jj * 4 + 3], ev.w, s3);
        }
        float s  = (s0 + s1) + (s2 + s3);
        float en = s * elg;
        e = (lane < TT) ? en : 0.0f;   // lanes>=TT keep 0 so lds_e[50..51]==0

        // constant-factor rescale (exact powers of two); wave-uniform branch
        if (__any(e > UP_THR)) {
            e *= 0x1p-64f; moff += OFF_64LN2;
        } else if (!__any(e > DOWN_THR)) {
            e *= 0x1p64f;  moff -= OFF_64LN2;
        }
        __builtin_amdgcn_wave_barrier();
    }

    // partition = logsumexp_i(log(e_i) + moff + trans[STOP, i])
    float v = (lane < TT) ? (moff + __logf(e) + trans[STOP_TAG * TT + lane])
                          : -INFINITY;
    float mm = v;
#pragma unroll
    for (int o = 32; o > 0; o >>= 1) mm = fmaxf(mm, __shfl_xor(mm, o));
    float ex = __expf(v - mm);           // -inf - finite = -inf -> 0
    float ssum = ex;
#pragma unroll
    for (int o = 32; o > 0; o >>= 1) ssum += __shfl_xor(ssum, o);
    if (lane == 0) part_out[b] = mm + __logf(ssum);
}

// ---------------- gold-path score (emission + transition) -------------------
__global__ __launch_bounds__(64) void crf_scores(
    const float* __restrict__ logits,
    const float* __restrict__ trans,
    const int* __restrict__ labels,     // [B, L]
    const int* __restrict__ lens,
    float* __restrict__ score_out)      // [B]
{
    const int b    = blockIdx.x;
    const int lane = threadIdx.x;
    const int len  = lens[b];

    float acc = 0.0f;
    for (int t = lane; t < len; t += 64) {
        int lab = labels[b * LL + t];
        acc += logits[((size_t)b * LL + t) * TT + lab];
        int prev = (t == 0) ? START_TAG : labels[b * LL + t - 1];
        acc += trans[lab * TT + prev];
    }
    if (lane == 0) acc += trans[STOP_TAG * TT + labels[b * LL + (len - 1)]];

#pragma unroll
    for (int o = 32; o > 0; o >>= 1) acc += __shfl_xor(acc, o);
    if (lane == 0) score_out[b] = acc;
}

// ---------------- final deterministic reduction ------------------------------
__global__ __launch_bounds__(1024) void crf_reduce(
    const float* __restrict__ part,
    const float* __restrict__ score,
    float* __restrict__ out)
{
    __shared__ float red[16];
    const int tid = threadIdx.x;
    float acc = part[tid] - score[tid];   // B == 1024 == blockDim
#pragma unroll
    for (int o = 32; o > 0; o >>= 1) acc += __shfl_xor(acc, o);
    const int w = tid >> 6;
    if ((tid & 63) == 0) red[w] = acc;
    __syncthreads();
    if (tid == 0) {
        float tot = 0.0f;
        for (int i = 0; i < 16; ++i) tot += red[i];
        out[0] = tot / (float)BB;
    }
}

extern "C" void kernel_launch(void* const* d_in, const int* in_sizes, int n_in,
                              void* d_out, int out_size, void* d_ws, size_t ws_size,
                              hipStream_t stream) {
    const float* logits = (const float*)d_in[0];
    const float* trans  = (const float*)d_in[1];
    const int*   labels = (const int*)d_in[2];
    const int*   lens   = (const int*)d_in[3];

    float* part  = (float*)d_ws;          // [B]
    float* score = part + BB;             // [B]
    float* out   = (float*)d_out;

    crf_forward<<<BB, 64, 0, stream>>>(logits, trans, lens, part);
    crf_scores<<<BB, 64, 0, stream>>>(logits, trans, labels, lens, score);
    crf_reduce<<<1, 1024, 0, stream>>>(part, score, out);
}

// Round 3
// 141.065 us; speedup vs baseline: 2.0985x; 1.6923x over previous
//
#include <hip/hip_runtime.h>

#define TT 50
#define START_TAG 48
#define STOP_TAG 49
#define BB 1024
#define LL 512

// Rescale constants: multiply by 2^-64 / 2^+64, offset by 64*ln2.
#define UP_THR   0x1p63f
#define DOWN_THR 0x1p-32f
#define OFF_64LN2 44.3614195558364998f

#define RING 16   // logits LDS ring slots (power of 2)
#define PF   8    // prefetch distance

typedef __attribute__((address_space(3))) uint32_t lds_u32_t;
typedef __attribute__((address_space(1))) const uint32_t glb_u32_t;

__device__ __forceinline__ void load_lds4(const float* g, float* l) {
    // dest = (uniform LDS base) + lane*4 ; src is per-lane global address
    __builtin_amdgcn_global_load_lds((glb_u32_t*)g, (lds_u32_t*)l, 4, 0, 0);
}

__device__ __forceinline__ float rdlane(uint32_t eu, int j) {
    return __uint_as_float(__builtin_amdgcn_readlane(eu, j));
}

// ---------------- forward (partition) kernel: one wave per sequence ----------
// Linear domain: e_{t+1} = exp(logit_t) * (M @ e_t), M = exp(trans).
// e broadcast via v_readlane (no LDS roundtrip); logits via global_load_lds
// ring with counted vmcnt (latency-proof prefetch).
__global__ __launch_bounds__(64) void crf_forward(
    const float* __restrict__ logits,   // [B, L, T]
    const float* __restrict__ trans,    // [T, T]
    const int* __restrict__ lens,       // [B]
    float* __restrict__ part_out)       // [B]
{
    const int b    = blockIdx.x;
    const int lane = threadIdx.x;
    const int len  = lens[b];

    __shared__ __align__(16) float ring[RING][64];   // 4 KB

    // M row `lane` in registers (rows >= TT use clamped row but never matter:
    // their e never feeds anything; row START is all exp(-1e4)=0 anyway).
    const int row_c = (lane < TT) ? lane : (TT - 1);
    float Mrow[TT];
#pragma unroll
    for (int j = 0; j < TT; ++j) {
        float m = __expf(trans[row_c * TT + j]);
        Mrow[j] = (lane < TT) ? m : 0.0f;
    }

    const int lane_c = (lane < TT) ? lane : (TT - 1);
    const float* gp = logits + (size_t)b * LL * TT + lane_c;

    // prologue: fill prefetch pipe
#pragma unroll
    for (int i = 0; i < PF; ++i) {
        int idx = (i < len) ? i : (len - 1);
        load_lds4(gp + (size_t)idx * TT, &ring[i][0]);
    }
    asm volatile("s_waitcnt vmcnt(6)" ::: "memory");   // slots 0,1 retired
    __builtin_amdgcn_sched_barrier(0);
    float elg = __expf(ring[0][lane]);                 // exp(logit_0)

    float e    = (lane == START_TAG) ? 1.0f : 0.0f;
    float moff = 0.0f;

    for (int t = 0; t < len; ++t) {
        // issue prefetch t+PF (clamped); the ONLY vmem op in the loop
        {
            int idx = t + PF; idx = (idx < len) ? idx : (len - 1);
            load_lds4(gp + (size_t)idx * TT, &ring[(t + PF) & (RING - 1)][0]);
        }

        // matvec: o = M @ e, e broadcast via readlane -> SGPR -> v_fma.
        // Column STOP(49) of M is exactly 0, skip its readlane.
        const uint32_t eu = __float_as_uint(e);
        float a0 = 0.f, a1 = 0.f, a2 = 0.f, a3 = 0.f;
#pragma unroll
        for (int j = 0; j < 48; j += 4) {
            float e0 = rdlane(eu, j + 0);
            float e1 = rdlane(eu, j + 1);
            float e2 = rdlane(eu, j + 2);
            float e3 = rdlane(eu, j + 3);
            a0 = fmaf(Mrow[j + 0], e0, a0);
            a1 = fmaf(Mrow[j + 1], e1, a1);
            a2 = fmaf(Mrow[j + 2], e2, a2);
            a3 = fmaf(Mrow[j + 3], e3, a3);
        }
        a0 = fmaf(Mrow[48], rdlane(eu, 48), a0);
        float s = (a0 + a1) + (a2 + a3);
        float en = s * elg;

        // wait for slot t+1 (issued 0..t+PF => vmcnt(6) guarantees t+1 retired
        // even if one issue slid past the asm), then read next logit from LDS.
        asm volatile("s_waitcnt vmcnt(6)" ::: "memory");
        __builtin_amdgcn_sched_barrier(0);
        float lgN = ring[(t + 1) & (RING - 1)][lane];

        // constant-factor rescale (exact powers of two); wave-uniform branch
        if (__any(en > UP_THR)) {
            en *= 0x1p-64f; moff += OFF_64LN2;
        } else if (!__any(en > DOWN_THR)) {
            en *= 0x1p64f;  moff -= OFF_64LN2;
        }
        e = en;
        elg = __expf(lgN);     // off the serial chain (consumed next iter)
    }

    // partition = logsumexp_i(log(e_i) + moff + trans[STOP, i])
    float v = (lane < TT) ? (moff + __logf(e) + trans[STOP_TAG * TT + lane])
                          : -INFINITY;
    float mm = v;
#pragma unroll
    for (int o = 32; o > 0; o >>= 1) mm = fmaxf(mm, __shfl_xor(mm, o));
    float ex = __expf(v - mm);           // -inf - finite = -inf -> 0
    float ssum = ex;
#pragma unroll
    for (int o = 32; o > 0; o >>= 1) ssum += __shfl_xor(ssum, o);
    if (lane == 0) part_out[b] = mm + __logf(ssum);
}

// ---------------- gold-path score (emission + transition) -------------------
__global__ __launch_bounds__(64) void crf_scores(
    const float* __restrict__ logits,
    const float* __restrict__ trans,
    const int* __restrict__ labels,     // [B, L]
    const int* __restrict__ lens,
    float* __restrict__ score_out)      // [B]
{
    const int b    = blockIdx.x;
    const int lane = threadIdx.x;
    const int len  = lens[b];

    float acc = 0.0f;
    for (int t = lane; t < len; t += 64) {
        int lab = labels[b * LL + t];
        acc += logits[((size_t)b * LL + t) * TT + lab];
        int prev = (t == 0) ? START_TAG : labels[b * LL + t - 1];
        acc += trans[lab * TT + prev];
    }
    if (lane == 0) acc += trans[STOP_TAG * TT + labels[b * LL + (len - 1)]];

#pragma unroll
    for (int o = 32; o > 0; o >>= 1) acc += __shfl_xor(acc, o);
    if (lane == 0) score_out[b] = acc;
}

// ---------------- final deterministic reduction ------------------------------
__global__ __launch_bounds__(1024) void crf_reduce(
    const float* __restrict__ part,
    const float* __restrict__ score,
    float* __restrict__ out)
{
    __shared__ float red[16];
    const int tid = threadIdx.x;
    float acc = part[tid] - score[tid];   // B == 1024 == blockDim
#pragma unroll
    for (int o = 32; o > 0; o >>= 1) acc += __shfl_xor(acc, o);
    const int w = tid >> 6;
    if ((tid & 63) == 0) red[w] = acc;
    __syncthreads();
    if (tid == 0) {
        float tot = 0.0f;
        for (int i = 0; i < 16; ++i) tot += red[i];
        out[0] = tot / (float)BB;
    }
}

extern "C" void kernel_launch(void* const* d_in, const int* in_sizes, int n_in,
                              void* d_out, int out_size, void* d_ws, size_t ws_size,
                              hipStream_t stream) {
    const float* logits = (const float*)d_in[0];
    const float* trans  = (const float*)d_in[1];
    const int*   labels = (const int*)d_in[2];
    const int*   lens   = (const int*)d_in[3];

    float* part  = (float*)d_ws;          // [B]
    float* score = part + BB;             // [B]
    float* out   = (float*)d_out;

    crf_forward<<<BB, 64, 0, stream>>>(logits, trans, lens, part);
    crf_scores<<<BB, 64, 0, stream>>>(logits, trans, labels, lens, score);
    crf_reduce<<<1, 1024, 0, stream>>>(part, score, out);
}

// Round 4
// 112.080 us; speedup vs baseline: 2.6412x; 1.2586x over previous
//
#include <hip/hip_runtime.h>

#define TT 50
#define START_TAG 48
#define STOP_TAG 49
#define BB 1024
#define LL 512

// Rescale: multiply by 2^±64, offset by 64*ln2. Checked every 2 steps:
// worst-case growth ~2^23/step => from <=2^63 reaches <=2^109 < 2^128. Safe.
#define UP_THR   0x1p63f
#define DOWN_THR 0x1p-32f
#define OFF_64LN2 44.3614195558364998f

#define RING 16   // LDS ring slots (power of 2)
#define PF   10   // prefetch distance; vmcnt(PF-2) => slot k+2 retired at step k

typedef __attribute__((address_space(3))) uint32_t lds_u32_t;
typedef __attribute__((address_space(1))) const uint32_t glb_u32_t;

__device__ __forceinline__ void load_lds4(const float* g, float* l) {
    __builtin_amdgcn_global_load_lds((glb_u32_t*)g, (lds_u32_t*)l, 4, 0, 0);
}
__device__ __forceinline__ float rdlane(uint32_t u, int j) {
    return __uint_as_float(__builtin_amdgcn_readlane(u, j));
}

// One recursion step. k, nsteps, len are wave-uniform (SALU address math).
// fwd: e' = (M @ e) * elg_t            (M[i][j] = exp(trans[i][j]))
// bwd: e' = M^T @ (e * elg_t)
template<bool BWD>
__device__ __forceinline__ void crf_step(
    float& e, float& moff, float& elg, float& lgN1,
    const float (&Mreg)[49], const float* __restrict__ gp,
    float (&ring)[RING][64], int lane, int k, int nsteps, int len, bool rescale)
{
    // prefetch slot k+PF (clamped index; ALWAYS exactly one issue per step
    // so the vmcnt(PF-2) arithmetic stays exact)
    {
        int kk = k + PF; int cl = nsteps - 1;
        kk = (kk > cl) ? cl : kk; kk = (kk < 0) ? 0 : kk;
        int t = BWD ? (len - 1 - kk) : kk;
        load_lds4(gp + (size_t)t * TT, &ring[(k + PF) & (RING - 1)][0]);
    }

    float elgN = __expf(lgN1);           // logit loaded 2 steps ago: off-chain

    float x = BWD ? (e * elg) : e;
    const uint32_t xu = __float_as_uint(x);
    float ebc[49];
#pragma unroll
    for (int j = 0; j < 49; ++j) {
        const int sl = BWD ? ((j < 48) ? j : 49) : j;   // bwd skips i=START(48); fwd skips j=STOP(49)
        ebc[j] = rdlane(xu, sl);
    }
    __builtin_amdgcn_sched_barrier(0);   // all readlanes before all FMAs

    float a0 = 0.f, a1 = 0.f, a2 = 0.f, a3 = 0.f;
#pragma unroll
    for (int j = 0; j < 48; j += 4) {
        a0 = fmaf(Mreg[j + 0], ebc[j + 0], a0);
        a1 = fmaf(Mreg[j + 1], ebc[j + 1], a1);
        a2 = fmaf(Mreg[j + 2], ebc[j + 2], a2);
        a3 = fmaf(Mreg[j + 3], ebc[j + 3], a3);
    }
    a0 = fmaf(Mreg[48], ebc[48], a0);
    float s = (a0 + a1) + (a2 + a3);

    float en = BWD ? s : s * elg;
    en = (lane < TT) ? en : 0.0f;

    if (rescale) {
        if (__any(en > UP_THR))          { en *= 0x1p-64f; moff += OFF_64LN2; }
        else if (!__any(en > DOWN_THR))  { en *= 0x1p64f;  moff -= OFF_64LN2; }
    }
    e = en;

    // slot k+2 retired: (prologue PF + k+1 issues) - (PF-2) kept => idx k+2 done
    asm volatile("s_waitcnt vmcnt(8)" ::: "memory");
    __builtin_amdgcn_sched_barrier(0);
    lgN1 = ring[(k + 2) & (RING - 1)][lane];
    elg = elgN;
}

template<bool BWD>
__device__ __forceinline__ void crf_body(
    int b, int lane,
    const float* __restrict__ logits, const float* __restrict__ trans,
    const int* __restrict__ lens,
    float* __restrict__ vec_out, float* __restrict__ scale_out,
    float (&ring)[RING][64])
{
    const int len    = lens[b];
    const int mid    = len >> 1;
    const int nsteps = BWD ? (len - mid) : mid;

    // M fragment in registers.
    // fwd: Mreg[k] = M[lane][k]      (row `lane`, cols 0..48)
    // bwd: Mreg[k] = M[sl(k)][lane]  (col `lane`, rows {0..47,49})
    float Mreg[49];
    {
        const int lc = (lane < TT) ? lane : 0;
#pragma unroll
        for (int k = 0; k < 49; ++k) {
            const int src = BWD ? ((k < 48) ? k : 49) : k;
            float tv = BWD ? trans[src * TT + lc] : trans[lc * TT + src];
            float m = __expf(tv);
            Mreg[k] = (lane < TT) ? m : 0.0f;
        }
    }

    const int lane_c = (lane < TT) ? lane : (TT - 1);
    const float* gp = logits + (size_t)b * LL * TT + lane_c;

    // prologue: fill prefetch pipe (clamped indices; len >= 1 always)
#pragma unroll
    for (int i = 0; i < PF; ++i) {
        int kk = i; int cl = nsteps - 1;
        kk = (kk > cl) ? cl : kk; kk = (kk < 0) ? 0 : kk;
        int t = BWD ? (len - 1 - kk) : kk;
        load_lds4(gp + (size_t)t * TT, &ring[i][0]);
    }
    asm volatile("s_waitcnt vmcnt(8)" ::: "memory");   // slots 0,1 retired
    __builtin_amdgcn_sched_barrier(0);
    float elg  = __expf(ring[0][lane]);
    float lgN1 = ring[1][lane];

    // state init
    float e = BWD ? ((lane < TT) ? __expf(trans[STOP_TAG * TT + lane]) : 0.0f)
                  : ((lane == START_TAG) ? 1.0f : 0.0f);
    float moff = 0.0f;

    int k = 0;
    for (; k + 2 <= nsteps; k += 2) {
        crf_step<BWD>(e, moff, elg, lgN1, Mreg, gp, ring, lane, k,     nsteps, len, false);
        crf_step<BWD>(e, moff, elg, lgN1, Mreg, gp, ring, lane, k + 1, nsteps, len, true);
    }
    if (k < nsteps)
        crf_step<BWD>(e, moff, elg, lgN1, Mreg, gp, ring, lane, k, nsteps, len, true);

    // normalize (max -> 1) and write vector + log-scale
    float mm = e;
#pragma unroll
    for (int o = 32; o > 0; o >>= 1) mm = fmaxf(mm, __shfl_xor(mm, o));
    vec_out[b * 64 + lane] = e * (1.0f / mm);
    if (lane == 0) scale_out[b] = moff + __logf(mm);
}

__global__ __launch_bounds__(64) void crf_fwdbwd(
    const float* __restrict__ logits, const float* __restrict__ trans,
    const int* __restrict__ lens,
    float* __restrict__ fvec, float* __restrict__ fs,
    float* __restrict__ bvec, float* __restrict__ bs)
{
    __shared__ __align__(16) float ring[RING][64];
    const int b   = blockIdx.x >> 1;
    const bool bw = blockIdx.x & 1;
    if (bw) crf_body<true >(b, threadIdx.x, logits, trans, lens, bvec, bs, ring);
    else    crf_body<false>(b, threadIdx.x, logits, trans, lens, fvec, fs, ring);
}

// ---------------- gold-path score (emission + transition) -------------------
__global__ __launch_bounds__(64) void crf_scores(
    const float* __restrict__ logits,
    const float* __restrict__ trans,
    const int* __restrict__ labels,
    const int* __restrict__ lens,
    float* __restrict__ score_out)
{
    const int b    = blockIdx.x;
    const int lane = threadIdx.x;
    const int len  = lens[b];

    float acc = 0.0f;
    for (int t = lane; t < len; t += 64) {
        int lab = labels[b * LL + t];
        acc += logits[((size_t)b * LL + t) * TT + lab];
        int prev = (t == 0) ? START_TAG : labels[b * LL + t - 1];
        acc += trans[lab * TT + prev];
    }
    if (lane == 0) acc += trans[STOP_TAG * TT + labels[b * LL + (len - 1)]];

#pragma unroll
    for (int o = 32; o > 0; o >>= 1) acc += __shfl_xor(acc, o);
    if (lane == 0) score_out[b] = acc;
}

// ---------------- combine: partition_b = log(f·b) + fs + bs ------------------
__global__ __launch_bounds__(64) void crf_combine(
    const float* __restrict__ fvec, const float* __restrict__ bvec,
    const float* __restrict__ fs,   const float* __restrict__ bs,
    const float* __restrict__ score, float* __restrict__ nll)
{
    const int b = blockIdx.x, lane = threadIdx.x;
    float p = fvec[b * 64 + lane] * bvec[b * 64 + lane];
#pragma unroll
    for (int o = 32; o > 0; o >>= 1) p += __shfl_xor(p, o);
    if (lane == 0) nll[b] = (__logf(p) + fs[b] + bs[b]) - score[b];
}

// ---------------- final deterministic reduction ------------------------------
__global__ __launch_bounds__(1024) void crf_reduce(
    const float* __restrict__ nll, float* __restrict__ out)
{
    __shared__ float red[16];
    const int tid = threadIdx.x;
    float acc = nll[tid];
#pragma unroll
    for (int o = 32; o > 0; o >>= 1) acc += __shfl_xor(acc, o);
    if ((tid & 63) == 0) red[tid >> 6] = acc;
    __syncthreads();
    if (tid == 0) {
        float tot = 0.0f;
        for (int i = 0; i < 16; ++i) tot += red[i];
        out[0] = tot / (float)BB;
    }
}

extern "C" void kernel_launch(void* const* d_in, const int* in_sizes, int n_in,
                              void* d_out, int out_size, void* d_ws, size_t ws_size,
                              hipStream_t stream) {
    const float* logits = (const float*)d_in[0];
    const float* trans  = (const float*)d_in[1];
    const int*   labels = (const int*)d_in[2];
    const int*   lens   = (const int*)d_in[3];

    float* fvec  = (float*)d_ws;            // [B*64]
    float* bvec  = fvec + BB * 64;          // [B*64]
    float* fs    = bvec + BB * 64;          // [B]
    float* bs    = fs + BB;                 // [B]
    float* score = bs + BB;                 // [B]
    float* nll   = score + BB;              // [B]
    float* out   = (float*)d_out;

    crf_fwdbwd<<<2 * BB, 64, 0, stream>>>(logits, trans, lens, fvec, fs, bvec, bs);
    crf_scores<<<BB, 64, 0, stream>>>(logits, trans, labels, lens, score);
    crf_combine<<<BB, 64, 0, stream>>>(fvec, bvec, fs, bs, score, nll);
    crf_reduce<<<1, 1024, 0, stream>>>(nll, out);
}